// Round 2
// baseline (411.045 us; speedup 1.0000x reference)
//
#include <hip/hip_runtime.h>
#include <math.h>

// GraphTrainNN: out[b] = prod_g  w2[g]*(wn[g] + w0[g]*x[b,g]^2) / (wn[g] + x[b,g]^2),
// wn = w1^2.  Memory-bound: 266 MB read / 2 MB write -> ~42.5 us floor @ 6.3 TB/s.
//
// R1 lesson: separate num/den running products BOTH underflow fp32 (ln pn ~ -197,
// ln pd ~ -76 +- 17) -> tail rows hit 0/0 = NaN. Fix: renormalize both mantissas
// with frexpf every 8 genes, track the exponent in an int, and finish with
// ldexpf(pn/pd, ex) -- underflows cleanly to 0/denormal like the fp32 reference.
//
// Layout: block = 64 threads = 64 rows. Stage 64x127 fp32 tile to LDS via
// coalesced float4 loads; thread == row; gene index is wave-uniform so weight
// reads broadcast (conflict-free) and x reads are a bank permutation (free
// 2-way wave64 aliasing only).

constexpr int G_GENES = 127;
constexpr int ROWS = 64;                         // rows per block == block size
constexpr int F4_PER_BLOCK = ROWS * G_GENES / 4; // 2032 float4 per x tile

__global__ __launch_bounds__(64)
void hill_prod_kernel(const float* __restrict__ x,
                      const float* __restrict__ w,
                      float* __restrict__ out)
{
    __shared__ float  xs[ROWS * G_GENES];  // 32512 B
    __shared__ float4 ws[G_GENES];         // (a=w0*w2, b=wn*w2, wn, pad) 2032 B

    const int tid = threadIdx.x;
    const size_t base = (size_t)blockIdx.x * (ROWS * G_GENES);

    // Stage per-gene constants (tiny; L2-resident across all 8192 blocks).
    for (int g = tid; g < G_GENES; g += ROWS) {
        float w0 = w[3 * g + 0];
        float w1 = w[3 * g + 1];
        float w2 = w[3 * g + 2];
        float wn = w1 * w1;
        ws[g] = make_float4(w0 * w2, wn * w2, wn, 0.0f);
    }

    // Stage x tile: 2032 float4, 16 B/lane fully coalesced.
    const float4* __restrict__ xg = reinterpret_cast<const float4*>(x + base);
    float4* xs4 = reinterpret_cast<float4*>(xs);
#pragma unroll
    for (int k = 0; k < 32; ++k) {
        int i = tid + k * ROWS;
        if (i < F4_PER_BLOCK) xs4[i] = xg[i];
    }
    __syncthreads();

    // Thread = row. Wave-uniform gene index -> broadcast weight reads.
    const float* __restrict__ xr = xs + tid * G_GENES;
    float pn = 1.0f, pd = 1.0f;
    int ex = 0;
#pragma unroll 8
    for (int g = 0; g < G_GENES; ++g) {
        float4 wv = ws[g];
        float xv = xr[g];
        float xn = xv * xv;
        float nv = fmaf(wv.x, xn, wv.y);  // w2*(wn + w0*xn), in [~1e-3, 2]
        float dv = wv.z + xn;             // wn + xn,         in [~0.01, 2]
        pn *= nv;
        pd *= dv;
        if ((g & 7) == 7) {
            // Renormalize: chunk of 8 keeps partials in [2^-80, 2^8] -- safe.
            int en, ed;
            pn = frexpf(pn, &en);         // mantissa in [0.5, 1)
            pd = frexpf(pd, &ed);
            ex += en - ed;
        }
    }
    // Final ratio is well-scaled; ldexpf underflows to 0/denormal gracefully,
    // matching the fp32 reference's own underflowed product.
    out[blockIdx.x * ROWS + tid] = ldexpf(pn / pd, ex);
}

extern "C" void kernel_launch(void* const* d_in, const int* in_sizes, int n_in,
                              void* d_out, int out_size, void* d_ws, size_t ws_size,
                              hipStream_t stream) {
    const float* x = (const float*)d_in[0];
    const float* w = (const float*)d_in[1];
    float* out = (float*)d_out;

    const int B = in_sizes[0] / G_GENES;  // 524288
    const int blocks = B / ROWS;          // 8192 (B is an exact multiple of 64)

    hipLaunchKernelGGL(hill_prod_kernel, dim3(blocks), dim3(ROWS), 0, stream,
                       x, w, out);
}